// Round 2
// baseline (519.996 us; speedup 1.0000x reference)
//
#include <hip/hip_runtime.h>
#include <hip/hip_bf16.h>
#include <stdint.h>

typedef __bf16 bf16_t;
typedef bf16_t bf16x4 __attribute__((ext_vector_type(4)));
typedef bf16_t bf16x8 __attribute__((ext_vector_type(8)));
typedef float f32x4 __attribute__((ext_vector_type(4)));

#define GAS __attribute__((address_space(1)))
#define LAS __attribute__((address_space(3)))

__device__ __forceinline__ void async_load16(const void* g, void* l) {
    __builtin_amdgcn_global_load_lds((const GAS void*)g, (LAS void*)l, 16, 0, 0);
}

// compiler-fence + HW barrier: empty asm stops load/store motion across the
// barrier (llvm.amdgcn.s.barrier alone is not a compiler memory fence).
__device__ __forceinline__ void hw_barrier() {
    asm volatile("" ::: "memory");
    __builtin_amdgcn_s_barrier();
    asm volatile("" ::: "memory");
}

// ---------- phase 1 (grid-stride): cast x->bf16  +  dequant W->bf16 ----------
__global__ __launch_bounds__(256) void prep_kernel(
    const float* __restrict__ x, bf16_t* __restrict__ xb,
    const int* __restrict__ wp, const float* __restrict__ cen,
    const float* __restrict__ scl, bf16_t* __restrict__ W,
    int castBlocks, long nCastChunks, int nDeqChunks)
{
    if ((int)blockIdx.x < castBlocks) {
        long idx    = (long)blockIdx.x * blockDim.x + threadIdx.x;
        long stride = (long)castBlocks * blockDim.x;
        const float4* xv = (const float4*)x;
        bf16x8* xo = (bf16x8*)xb;
        for (long t = idx; t < nCastChunks; t += stride) {
            float4 a = xv[2 * t];
            float4 b = xv[2 * t + 1];
            bf16x8 o;
            o[0] = (bf16_t)a.x; o[1] = (bf16_t)a.y; o[2] = (bf16_t)a.z; o[3] = (bf16_t)a.w;
            o[4] = (bf16_t)b.x; o[5] = (bf16_t)b.y; o[6] = (bf16_t)b.z; o[7] = (bf16_t)b.w;
            xo[t] = o;
        }
    } else {
        __shared__ float c[16];
        if (threadIdx.x < 16) c[threadIdx.x] = cen[threadIdx.x];
        __syncthreads();
        int  nb     = (int)gridDim.x - castBlocks;
        long idx    = (long)((int)blockIdx.x - castBlocks) * blockDim.x + threadIdx.x;
        long stride = (long)nb * blockDim.x;
        const int4* wv = (const int4*)wp;
        bf16x8* wo = (bf16x8*)W;
        for (long t = idx; t < (long)nDeqChunks; t += stride) {
            int4 v = wv[t];
            long p   = t << 2;
            int  o   = (int)(p >> 11);
            int  pin = (int)p & 2047;
            float s = scl[(o << 6) + (pin >> 5)];
            int vv[4] = {v.x, v.y, v.z, v.w};
            bf16x8 outv;
#pragma unroll
            for (int i = 0; i < 4; ++i) {
                int b = vv[i];
                outv[2 * i]     = (bf16_t)(c[(b >> 4) & 15] * s);
                outv[2 * i + 1] = (bf16_t)(c[b & 15] * s);
            }
            wo[t] = outv;
        }
    }
}

// ---------------- phase 2: bf16 NT GEMM, 256x256 tile, BK=64 ----------------
// 8 waves (2M x 4N), per-wave output 128x64 (acc[8][4] f32x4).
// LDS: 2 x (A 256x64 + B 256x64) bf16 = 128 KB double buffer.
// Schedule (2-tile lookahead, counted vmcnt — never 0 in steady state):
//   prologue: stage tile0->buf0, tile1->buf1; vmcnt(8); barrier
//   iter j (buf c=j&1):
//     phase A: ds_read all B frags + A frags mf0..3; 32 MFMA (setprio-wrapped)
//     phase B: ds_read A frags mf4..7;               32 MFMA
//     barrier                  // all waves done reading buf c
//     stage tile j+2 -> buf c  // 8 global_load_lds per wave
//     vmcnt(8)                 // own tile-(j+1) loads landed (last 8 = tile j+2)
//     barrier                  // collective: buf c^1 ready for iter j+1
// Race check: writes into buf c are issued only after the barrier ending all
// collective reads of buf c; reads of buf c^1 happen only after each wave's
// vmcnt(8) + barrier (all waves' tile-(j+1) loads retired).
// XOR swizzle at 16B-chunk granularity as before: (row,kc)->slot kc^(row&7),
// global source pre-swizzled, LDS dest linear (bank-conflict = 0, verified).
#define BM 256
#define BN 256
#define BK 64

__global__ __launch_bounds__(512, 2) void gemm_bf16_nt(
    const bf16_t* __restrict__ A, const bf16_t* __restrict__ B,
    float* __restrict__ C, int M, int N, int K)
{
    __shared__ bf16_t lA[2][BM * BK];   // 2 x 32 KB
    __shared__ bf16_t lB[2][BN * BK];   // 2 x 32 KB

    const int tid  = threadIdx.x;
    const int wave = tid >> 6;
    const int lane = tid & 63;
    const int wmB  = (wave >> 2) * 128;   // wave M base in tile
    const int wnB  = (wave & 3) * 64;     // wave N base in tile

    // XCD-aware block swizzle (nwg = 512, divisible by 8 -> simple form valid)
    const int nwg = (int)gridDim.x;
    const int cpx = nwg >> 3;
    const int bid = (int)blockIdx.x;
    const int swz = (bid & 7) * cpx + (bid >> 3);
    const int nx  = N / BN;
    const int by  = swz / nx;
    const int bx  = swz - by * nx;
    const long m0 = (long)by * BM;
    const long n0 = (long)bx * BN;

    // staging: 2048 16B-chunks per matrix per K-tile = 4 rounds x 512 threads.
    // slot s = r*512+tid: row=s>>3, kc_slot=s&7, global kc = kc_slot^(row&7).
    int offA[4], offB[4], ldsOff[4];
#pragma unroll
    for (int r = 0; r < 4; ++r) {
        int s   = r * 512 + tid;
        int row = s >> 3;
        int kg  = (s & 7) ^ (row & 7);
        offA[r] = (int)(m0 + row) * K + kg * 8;   // fits 32-bit (max ~33.5M)
        offB[r] = (int)(n0 + row) * K + kg * 8;
        ldsOff[r] = (r * 512 + wave * 64) * 8;    // wave-uniform elem offset
    }

    auto stage = [&](int buf, int k0) {
#pragma unroll
        for (int r = 0; r < 4; ++r) async_load16(A + offA[r] + k0, &lA[buf][ldsOff[r]]);
#pragma unroll
        for (int r = 0; r < 4; ++r) async_load16(B + offB[r] + k0, &lB[buf][ldsOff[r]]);
    };

    // fragment reads: row = base + frag*16 + qm; chunk co = (kc ^ (qm&7))*8
    const int qm  = lane & 15;
    const int kcb = lane >> 4;                 // 0..3
    const int co0 = (kcb ^ (qm & 7)) * 8;      // K half 0
    const int co1 = ((kcb + 4) ^ (qm & 7)) * 8; // K half 1

    f32x4 acc[8][4] = {};

    stage(0, 0);
    stage(1, BK);
    asm volatile("s_waitcnt vmcnt(8)" ::: "memory");   // tile0 landed (own)
    hw_barrier();                                       // collective

    const int NT = K / BK;
    for (int j = 0; j < NT; ++j) {
        const int c = j & 1;
        const bf16_t* la = &lA[c][0];
        const bf16_t* lb = &lB[c][0];

        bf16x8 bfv[4][2], af[4][2];
#pragma unroll
        for (int nf = 0; nf < 4; ++nf) {
            const bf16_t* pb = lb + (wnB + nf * 16 + qm) * BK;
            bfv[nf][0] = *(const bf16x8*)(pb + co0);
            bfv[nf][1] = *(const bf16x8*)(pb + co1);
        }
#pragma unroll
        for (int mf = 0; mf < 4; ++mf) {
            const bf16_t* pa = la + (wmB + mf * 16 + qm) * BK;
            af[mf][0] = *(const bf16x8*)(pa + co0);
            af[mf][1] = *(const bf16x8*)(pa + co1);
        }
        __builtin_amdgcn_s_setprio(1);
#pragma unroll
        for (int mf = 0; mf < 4; ++mf)
#pragma unroll
            for (int nf = 0; nf < 4; ++nf) {
                acc[mf][nf] = __builtin_amdgcn_mfma_f32_16x16x32_bf16(af[mf][0], bfv[nf][0], acc[mf][nf], 0, 0, 0);
                acc[mf][nf] = __builtin_amdgcn_mfma_f32_16x16x32_bf16(af[mf][1], bfv[nf][1], acc[mf][nf], 0, 0, 0);
            }
        __builtin_amdgcn_s_setprio(0);
        // phase B: A frags mf 4..7 (reuse af regs)
#pragma unroll
        for (int mf = 0; mf < 4; ++mf) {
            const bf16_t* pa = la + (wmB + (mf + 4) * 16 + qm) * BK;
            af[mf][0] = *(const bf16x8*)(pa + co0);
            af[mf][1] = *(const bf16x8*)(pa + co1);
        }
        __builtin_amdgcn_s_setprio(1);
#pragma unroll
        for (int mf = 0; mf < 4; ++mf)
#pragma unroll
            for (int nf = 0; nf < 4; ++nf) {
                acc[mf + 4][nf] = __builtin_amdgcn_mfma_f32_16x16x32_bf16(af[mf][0], bfv[nf][0], acc[mf + 4][nf], 0, 0, 0);
                acc[mf + 4][nf] = __builtin_amdgcn_mfma_f32_16x16x32_bf16(af[mf][1], bfv[nf][1], acc[mf + 4][nf], 0, 0, 0);
            }
        __builtin_amdgcn_s_setprio(0);

        hw_barrier();                          // all reads of buf c complete
        if (j + 2 < NT) {
            stage(c, (j + 2) * BK);
            asm volatile("s_waitcnt vmcnt(8)" ::: "memory");  // tile j+1 landed (own)
        } else if (j + 1 < NT) {
            asm volatile("s_waitcnt vmcnt(0)" ::: "memory");  // drain final tile
        }
        hw_barrier();                          // collective: buf c^1 ready
    }

    // C/D layout: col = lane&15, row = (lane>>4)*4 + reg   [m89-verified]
    const int crow = (lane >> 4) * 4;
    const int ccol = lane & 15;
#pragma unroll
    for (int mf = 0; mf < 8; ++mf)
#pragma unroll
        for (int r = 0; r < 4; ++r) {
            float* cp = C + (m0 + wmB + mf * 16 + crow + r) * (long)N + (n0 + wnB + ccol);
#pragma unroll
            for (int nf = 0; nf < 4; ++nf)
                cp[nf * 16] = acc[mf][nf][r];
        }
}

// ---------------- fallback (only if ws too small): fused, slow, correct ----------------
__global__ void fallback_qgemm(const float* __restrict__ x, const int* __restrict__ wp,
                               const float* __restrict__ cen, const float* __restrict__ scl,
                               float* __restrict__ out, int M, int N, int Kp) {
    __shared__ float c[16];
    if (threadIdx.x < 16) c[threadIdx.x] = cen[threadIdx.x];
    __syncthreads();
    int n = blockIdx.x * blockDim.x + threadIdx.x;
    int m = blockIdx.y;
    if (n >= N) return;
    const float* xr = x + (long)m * (Kp * 2);
    const int*   wr = wp + (long)n * Kp;
    int nb = Kp / 32;
    float acc = 0.f;
    for (int b = 0; b < nb; ++b) {
        float s  = scl[n * nb + b];
        float pa = 0.f;
        for (int j = 0; j < 32; ++j) {
            int v = wr[b * 32 + j];
            pa += xr[(b * 32 + j) * 2]     * c[(v >> 4) & 15]
                + xr[(b * 32 + j) * 2 + 1] * c[v & 15];
        }
        acc += s * pa;
    }
    out[(long)m * N + n] = acc;
}

extern "C" void kernel_launch(void* const* d_in, const int* in_sizes, int n_in,
                              void* d_out, int out_size, void* d_ws, size_t ws_size,
                              hipStream_t stream) {
    const float* x   = (const float*)d_in[0];
    const int*   wp  = (const int*)d_in[1];
    const float* cen = (const float*)d_in[2];
    const float* scl = (const float*)d_in[3];
    float* out = (float*)d_out;

    const int  IN  = 4096;
    const int  OUT = 4096;
    const long M   = (long)in_sizes[0] / IN;   // 8192

    size_t need = (size_t)(M * IN + (long)OUT * IN) * sizeof(bf16_t);  // 96 MB
    if (ws_size >= need && (M % BM) == 0) {
        bf16_t* xb = (bf16_t*)d_ws;
        bf16_t* Wb = xb + M * IN;
        const int castBlocks = 2048;
        const int deqBlocks  = 512;
        long nCastChunks = M * IN / 8;
        int  nDeqChunks  = OUT * (IN / 2) / 4;
        prep_kernel<<<dim3(castBlocks + deqBlocks), dim3(256), 0, stream>>>(
            x, xb, wp, cen, scl, Wb, castBlocks, nCastChunks, nDeqChunks);
        int nwg = (OUT / BN) * (int)(M / BM);   // 16 * 32 = 512
        gemm_bf16_nt<<<dim3(nwg), dim3(512), 0, stream>>>(xb, Wb, out, (int)M, OUT, IN);
    } else {
        dim3 grid(OUT / 256, (unsigned)M);
        fallback_qgemm<<<grid, dim3(256), 0, stream>>>(x, wp, cen, scl, out, (int)M, OUT, IN / 2);
    }
}